// Round 1
// baseline (168.135 us; speedup 1.0000x reference)
//
#include <hip/hip_runtime.h>
#include <hip/hip_bf16.h>
#include <stdint.h>

#define NTOK 4096
#define DIM  256
#define HID  1024
#define NEXP 8
#define MTILE 64
#define HC 64
#define HSLICE 512

typedef float f32x4 __attribute__((ext_vector_type(4)));
typedef short s16x8 __attribute__((ext_vector_type(8)));
typedef short s16x4 __attribute__((ext_vector_type(4)));

__device__ __forceinline__ unsigned short f2bf(float f) {
  union { float f; unsigned u; } v; v.f = f;
  unsigned r = v.u + 0x7FFFu + ((v.u >> 16) & 1u);
  return (unsigned short)(r >> 16);
}

__device__ __forceinline__ void mfma16(f32x4& acc, s16x8 a, s16x8 b) {
  asm("v_mfma_f32_16x16x32_bf16 %0, %1, %2, %0" : "+v"(acc) : "v"(a), "v"(b));
}
__device__ __forceinline__ void accfence(f32x4& a) {   // MFMA->VALU read hazard
  asm volatile("s_nop 7" : "+v"(a));
}
__device__ __forceinline__ void initfence(f32x4& a) {  // VALU init -> MFMA srcC hazard
  asm volatile("s_nop 1" : "+v"(a));
}

// ---- transpose + f32->bf16 : in [E][R][C] f32 -> out [E][C][R] bf16 ----
__global__ __launch_bounds__(256) void tr_cvt(const float* __restrict__ in,
                                              unsigned short* __restrict__ out,
                                              int R, int C) {
  __shared__ float tile[32][33];
  int e = blockIdx.z;
  int r0 = blockIdx.y * 32, c0 = blockIdx.x * 32;
  int tx = threadIdx.x, ty = threadIdx.y;
  const float* ip = in + (size_t)e * R * C;
  unsigned short* op = out + (size_t)e * R * C;
  #pragma unroll
  for (int k = 0; k < 4; ++k)
    tile[ty + 8*k][tx] = ip[(size_t)(r0 + ty + 8*k) * C + c0 + tx];
  __syncthreads();
  #pragma unroll
  for (int k = 0; k < 4; ++k)
    op[(size_t)(c0 + ty + 8*k) * R + r0 + tx] = f2bf(tile[tx][ty + 8*k]);
}

// ---- gate scores, top-2, routing lists, x -> bf16 (one wave per token) ----
__global__ __launch_bounds__(256) void gate_route(const float* __restrict__ x,
    const float* __restrict__ gW, const float* __restrict__ gb,
    const float* __restrict__ temp,
    int* __restrict__ counts, int* __restrict__ list,
    unsigned short* __restrict__ xbf) {
  int lane = threadIdx.x & 63;
  int n = blockIdx.x * 4 + (threadIdx.x >> 6);
  float4 xv = *reinterpret_cast<const float4*>(x + (size_t)n * DIM + 4 * lane);
  s16x4 xb;
  xb.x = (short)f2bf(xv.x); xb.y = (short)f2bf(xv.y);
  xb.z = (short)f2bf(xv.z); xb.w = (short)f2bf(xv.w);
  *reinterpret_cast<s16x4*>(xbf + (size_t)n * DIM + 4 * lane) = xb;

  float acc[NEXP];
  #pragma unroll
  for (int e = 0; e < NEXP; ++e) {
    float4 wv = *reinterpret_cast<const float4*>(gW + (size_t)e * DIM + 4 * lane);
    acc[e] = xv.x*wv.x + xv.y*wv.y + xv.z*wv.z + xv.w*wv.w;
  }
  #pragma unroll
  for (int off = 32; off; off >>= 1) {
    #pragma unroll
    for (int e = 0; e < NEXP; ++e) acc[e] += __shfl_xor(acc[e], off);
  }
  if (lane == 0) {
    float t = temp[0];
    float s[NEXP];
    #pragma unroll
    for (int e = 0; e < NEXP; ++e) s[e] = (acc[e] + gb[e]) / t;
    int b0 = 0; float v0 = s[0];
    #pragma unroll
    for (int e = 1; e < NEXP; ++e) if (s[e] > v0) { v0 = s[e]; b0 = e; }
    int b1i = 0; float v1 = -3.4e38f;
    #pragma unroll
    for (int e = 0; e < NEXP; ++e) if (e != b0 && s[e] > v1) { v1 = s[e]; b1i = e; }
    int p0 = atomicAdd(&counts[b0], 1);
    list[b0 * NTOK + p0] = n;
    int p1 = atomicAdd(&counts[b1i], 1);
    list[b1i * NTOK + p1] = n;
  }
}

// ---- fused per-expert FFN: y = relu(X W1 + b1) W2 + b2, scatter-add ----
__global__ __launch_bounds__(256, 2) void moe_ffn(
    const unsigned short* __restrict__ xbf,
    const unsigned short* __restrict__ W1T,  // [E][H][D] bf16
    const unsigned short* __restrict__ W2T,  // [E][D][H] bf16
    const float* __restrict__ b1g, const float* __restrict__ b2g,
    const int* __restrict__ counts, const int* __restrict__ list,
    float* __restrict__ out) {
  int b = blockIdx.x;
  int e = b & 7;
  int r = b >> 3;
  int s = r & 1;
  int t = r >> 1;
  int cnt = counts[e];
  if (t * MTILE >= cnt) return;

  __shared__ __align__(16) short Xs[64][264];
  __shared__ __align__(16) short Ws[18432];   // W1 chunk [64][264] or W2 chunk [256][72]
  __shared__ __align__(16) short hs[64][72];

  int tid = threadIdx.x;
  int l = tid & 63, w = tid >> 6;
  int lr = l & 15, lg = l >> 4, kg = lg * 8;
  const int* mylist = list + e * NTOK + t * MTILE;

  // stage gathered X tile (bf16)
  #pragma unroll
  for (int p = 0; p < 8; ++p) {
    int c = tid + p * 256;
    int row = c >> 5, col = (c & 31) * 8;
    int grow = t * MTILE + row;
    int ntok = (grow < cnt) ? mylist[row] : 0;
    *(s16x8*)&Xs[row][col] = *(const s16x8*)(xbf + (size_t)ntok * DIM + col);
  }

  f32x4 acc[4][4] = {};
  int aq = (w & 1) * 32, bq = (w >> 1) * 32;
  int hoff = s * HSLICE;

  for (int c = 0; c < HSLICE / HC; ++c) {
    int hc = hoff + c * HC;
    __syncthreads();  // prev GEMM2 done with Ws/hs (also covers Xs staging on c=0)
    { // stage W1 chunk: Ws[j][0..255] = W1T[e][hc+j][:]
      const unsigned short* src = W1T + ((size_t)e * HID + hc) * DIM;
      #pragma unroll
      for (int p = 0; p < 8; ++p) {
        int cc = tid + p * 256;
        int j = cc >> 5, col = (cc & 31) * 8;
        *(s16x8*)&Ws[j * 264 + col] = *(const s16x8*)(src + j * DIM + col);
      }
    }
    __syncthreads();
    { // GEMM1: h = relu(Xs @ W1chunk + b1) -> hs
      f32x4 ha[2][2] = {};
      initfence(ha[0][0]); initfence(ha[0][1]); initfence(ha[1][0]); initfence(ha[1][1]);
      #pragma unroll
      for (int kb = 0; kb < 256; kb += 32) {
        s16x8 av0 = *(const s16x8*)&Xs[aq + lr][kb + kg];
        s16x8 av1 = *(const s16x8*)&Xs[aq + 16 + lr][kb + kg];
        s16x8 bv0 = *(const s16x8*)&Ws[(bq + lr) * 264 + kb + kg];
        s16x8 bv1 = *(const s16x8*)&Ws[(bq + 16 + lr) * 264 + kb + kg];
        mfma16(ha[0][0], av0, bv0);
        mfma16(ha[0][1], av0, bv1);
        mfma16(ha[1][0], av1, bv0);
        mfma16(ha[1][1], av1, bv1);
      }
      accfence(ha[0][0]); accfence(ha[0][1]); accfence(ha[1][0]); accfence(ha[1][1]);
      #pragma unroll
      for (int n = 0; n < 2; ++n) {
        float bb = b1g[e * HID + hc + bq + n * 16 + lr];
        #pragma unroll
        for (int m = 0; m < 2; ++m) {
          #pragma unroll
          for (int q = 0; q < 4; ++q) {
            float hv = fmaxf(ha[m][n][q] + bb, 0.f);
            hs[aq + m * 16 + lg * 4 + q][bq + n * 16 + lr] = (short)f2bf(hv);
          }
        }
      }
    }
    __syncthreads();
    { // stage W2 chunk: Ws[d][0..63] = W2T[e][d][hc..hc+64]
      const unsigned short* src = W2T + (size_t)e * DIM * HID + hc;
      #pragma unroll
      for (int p = 0; p < 8; ++p) {
        int cc = tid + p * 256;
        int d = cc >> 3, col = (cc & 7) * 8;
        *(s16x8*)&Ws[d * 72 + col] = *(const s16x8*)(src + (size_t)d * HID + col);
      }
    }
    __syncthreads();
    { // GEMM2: acc += hs @ W2chunk   (wave w owns output cols [64w, 64w+64))
      #pragma unroll
      for (int kb = 0; kb < HC; kb += 32) {
        s16x8 a4[4], b4[4];
        #pragma unroll
        for (int m = 0; m < 4; ++m) a4[m] = *(const s16x8*)&hs[m * 16 + lr][kb + kg];
        #pragma unroll
        for (int n = 0; n < 4; ++n) b4[n] = *(const s16x8*)&Ws[(w * 64 + n * 16 + lr) * 72 + kb + kg];
        #pragma unroll
        for (int m = 0; m < 4; ++m) {
          #pragma unroll
          for (int n = 0; n < 4; ++n) mfma16(acc[m][n], a4[m], b4[n]);
        }
      }
    }
  }

  // epilogue: scatter-add (+b2 once, from slice 0)
  #pragma unroll
  for (int m = 0; m < 4; ++m) {
    #pragma unroll
    for (int n = 0; n < 4; ++n) accfence(acc[m][n]);
  }
  #pragma unroll
  for (int m = 0; m < 4; ++m) {
    #pragma unroll
    for (int q = 0; q < 4; ++q) {
      int lrow = m * 16 + lg * 4 + q;
      int grow = t * MTILE + lrow;
      if (grow < cnt) {
        int ntok = mylist[lrow];
        #pragma unroll
        for (int n = 0; n < 4; ++n) {
          int d = w * 64 + n * 16 + lr;
          float v = acc[m][n][q];
          if (s == 0) v += b2g[e * DIM + d];
          atomicAdd(out + (size_t)ntok * DIM + d, v);
        }
      }
    }
  }
}

extern "C" void kernel_launch(void* const* d_in, const int* in_sizes, int n_in,
                              void* d_out, int out_size, void* d_ws, size_t ws_size,
                              hipStream_t stream) {
  const float* x    = (const float*)d_in[0];
  const float* gW   = (const float*)d_in[1];
  const float* gb   = (const float*)d_in[2];
  const float* W1   = (const float*)d_in[3];
  const float* b1   = (const float*)d_in[4];
  const float* W2   = (const float*)d_in[5];
  const float* b2   = (const float*)d_in[6];
  const float* temp = (const float*)d_in[7];
  float* out = (float*)d_out;

  char* ws = (char*)d_ws;
  int*            counts = (int*)(ws + 0);                      // 256 B
  int*            list   = (int*)(ws + 256);                    // 8*4096*4 = 131072 B
  unsigned short* xbf    = (unsigned short*)(ws + 131584);      // 2 MB
  unsigned short* W1T    = (unsigned short*)(ws + 2228736);     // 4 MB
  unsigned short* W2T    = (unsigned short*)(ws + 6423040);     // 4 MB  (total ~10.2 MB)

  hipMemsetAsync(counts, 0, 256, stream);
  hipMemsetAsync(d_out, 0, (size_t)out_size * sizeof(float), stream);

  tr_cvt<<<dim3(HID/32, DIM/32, NEXP), dim3(32, 8, 1), 0, stream>>>(W1, W1T, DIM, HID);
  tr_cvt<<<dim3(DIM/32, HID/32, NEXP), dim3(32, 8, 1), 0, stream>>>(W2, W2T, HID, DIM);
  gate_route<<<NTOK/4, 256, 0, stream>>>(x, gW, gb, temp, counts, list, xbf);
  moe_ffn<<<NEXP * (NTOK/MTILE) * 2, 256, 0, stream>>>(xbf, W1T, W2T, b1, b2, counts, list, out);
}

// Round 2
// 94.613 us; speedup vs baseline: 1.7771x; 1.7771x over previous
//
#include <hip/hip_runtime.h>
#include <hip/hip_bf16.h>
#include <stdint.h>

#define NTOK 4096
#define DIM  256
#define HID  1024
#define NEXP 8
#define MTILE 64
#define HC 64
#define HSLICE 512

typedef float f32x4 __attribute__((ext_vector_type(4)));
typedef short s16x8 __attribute__((ext_vector_type(8)));
typedef short s16x4 __attribute__((ext_vector_type(4)));

__device__ __forceinline__ unsigned short f2bf(float f) {
  union { float f; unsigned u; } v; v.f = f;
  unsigned r = v.u + 0x7FFFu + ((v.u >> 16) & 1u);
  return (unsigned short)(r >> 16);
}

__device__ __forceinline__ void mfma16(f32x4& acc, s16x8 a, s16x8 b) {
  asm("v_mfma_f32_16x16x32_bf16 %0, %1, %2, %0" : "+v"(acc) : "v"(a), "v"(b));
}
__device__ __forceinline__ void accfence(f32x4& a) {   // MFMA->VALU read hazard
  asm volatile("s_nop 7" : "+v"(a));
}
__device__ __forceinline__ void initfence(f32x4& a) {  // VALU init -> MFMA srcC hazard
  asm volatile("s_nop 1" : "+v"(a));
}

// ---- transpose + f32->bf16 : in [E][R][C] f32 -> out [E][C][R] bf16 ----
__global__ __launch_bounds__(256) void tr_cvt(const float* __restrict__ in,
                                              unsigned short* __restrict__ out,
                                              int R, int C) {
  __shared__ float tile[32][33];
  int e = blockIdx.z;
  int r0 = blockIdx.y * 32, c0 = blockIdx.x * 32;
  int tx = threadIdx.x, ty = threadIdx.y;
  const float* ip = in + (size_t)e * R * C;
  unsigned short* op = out + (size_t)e * R * C;
  #pragma unroll
  for (int k = 0; k < 4; ++k)
    tile[ty + 8*k][tx] = ip[(size_t)(r0 + ty + 8*k) * C + c0 + tx];
  __syncthreads();
  #pragma unroll
  for (int k = 0; k < 4; ++k)
    op[(size_t)(c0 + ty + 8*k) * R + r0 + tx] = f2bf(tile[tx][ty + 8*k]);
}

// ---- gate + top-2 + block-aggregated routing (64 tokens/block) ----
__global__ __launch_bounds__(256) void gate_route(const float* __restrict__ x,
    const float* __restrict__ gW, const float* __restrict__ gb,
    const float* __restrict__ temp,
    int* __restrict__ counts, int* __restrict__ list,
    unsigned short* __restrict__ xbf) {
  __shared__ int pairs[64][2];
  __shared__ int lcnt[NEXP], lbase[NEXP], lrank[NEXP];
  int tid = threadIdx.x;
  int w = tid >> 6, lane = tid & 63;
  if (tid < NEXP) { lcnt[tid] = 0; lrank[tid] = 0; }
  __syncthreads();
  int t0 = blockIdx.x * 64;

  for (int i = 0; i < 16; ++i) {
    int tok = w * 16 + i;
    int n = t0 + tok;
    float4 xv = *reinterpret_cast<const float4*>(x + (size_t)n * DIM + 4 * lane);
    s16x4 xb;
    xb.x = (short)f2bf(xv.x); xb.y = (short)f2bf(xv.y);
    xb.z = (short)f2bf(xv.z); xb.w = (short)f2bf(xv.w);
    *reinterpret_cast<s16x4*>(xbf + (size_t)n * DIM + 4 * lane) = xb;

    float acc[NEXP];
    #pragma unroll
    for (int e = 0; e < NEXP; ++e) {
      float4 wv = *reinterpret_cast<const float4*>(gW + (size_t)e * DIM + 4 * lane);
      acc[e] = xv.x*wv.x + xv.y*wv.y + xv.z*wv.z + xv.w*wv.w;
    }
    #pragma unroll
    for (int off = 32; off; off >>= 1) {
      #pragma unroll
      for (int e = 0; e < NEXP; ++e) acc[e] += __shfl_xor(acc[e], off);
    }
    if (lane == 0) {
      float t = temp[0];
      float s[NEXP];
      #pragma unroll
      for (int e = 0; e < NEXP; ++e) s[e] = (acc[e] + gb[e]) / t;
      int b0 = 0; float v0 = s[0];
      #pragma unroll
      for (int e = 1; e < NEXP; ++e) if (s[e] > v0) { v0 = s[e]; b0 = e; }
      int b1i = 0; float v1 = -3.4e38f;
      #pragma unroll
      for (int e = 0; e < NEXP; ++e) if (e != b0 && s[e] > v1) { v1 = s[e]; b1i = e; }
      pairs[tok][0] = b0;
      pairs[tok][1] = b1i;
      atomicAdd(&lcnt[b0], 1);
      atomicAdd(&lcnt[b1i], 1);
    }
  }
  __syncthreads();
  if (tid < NEXP) lbase[tid] = atomicAdd(&counts[tid], lcnt[tid]);
  __syncthreads();
  if (tid < 128) {
    int tok = tid >> 1;
    int e = pairs[tok][tid & 1];
    int r = atomicAdd(&lrank[e], 1);
    list[e * NTOK + lbase[e] + r] = t0 + tok;
  }
}

// ---- fused per-expert FFN: y = relu(X W1 + b1) W2 + b2, scatter-add ----
__global__ __launch_bounds__(256, 2) void moe_ffn(
    const unsigned short* __restrict__ xbf,
    const unsigned short* __restrict__ W1T,  // [E][H][D] bf16
    const unsigned short* __restrict__ W2T,  // [E][D][H] bf16
    const float* __restrict__ b1g, const float* __restrict__ b2g,
    const int* __restrict__ counts, const int* __restrict__ list,
    float* __restrict__ out) {
  int b = blockIdx.x;
  int e = b & 7;
  int r = b >> 3;
  int s = r & 1;
  int t = r >> 1;
  int cnt = counts[e];
  if (t * MTILE >= cnt) return;

  __shared__ __align__(16) short Xs[64][264];
  __shared__ __align__(16) short Ws[18432];   // W1 chunk [64][264] or W2 chunk [256][72]
  __shared__ __align__(16) short hs[64][72];

  int tid = threadIdx.x;
  int l = tid & 63, w = tid >> 6;
  int lr = l & 15, lg = l >> 4, kg = lg * 8;
  const int* mylist = list + e * NTOK + t * MTILE;

  // stage gathered X tile (bf16)
  #pragma unroll
  for (int p = 0; p < 8; ++p) {
    int c = tid + p * 256;
    int row = c >> 5, col = (c & 31) * 8;
    int grow = t * MTILE + row;
    int ntok = (grow < cnt) ? mylist[row] : 0;
    *(s16x8*)&Xs[row][col] = *(const s16x8*)(xbf + (size_t)ntok * DIM + col);
  }

  f32x4 acc[4][4] = {};
  int aq = (w & 1) * 32, bq = (w >> 1) * 32;
  int hoff = s * HSLICE;

  for (int c = 0; c < HSLICE / HC; ++c) {
    int hc = hoff + c * HC;
    __syncthreads();  // prev GEMM2 done with Ws/hs (also covers Xs staging on c=0)
    { // stage W1 chunk: Ws[j][0..255] = W1T[e][hc+j][:]
      const unsigned short* src = W1T + ((size_t)e * HID + hc) * DIM;
      #pragma unroll
      for (int p = 0; p < 8; ++p) {
        int cc = tid + p * 256;
        int j = cc >> 5, col = (cc & 31) * 8;
        *(s16x8*)&Ws[j * 264 + col] = *(const s16x8*)(src + j * DIM + col);
      }
    }
    __syncthreads();
    { // GEMM1: h = relu(Xs @ W1chunk + b1) -> hs
      f32x4 ha[2][2] = {};
      initfence(ha[0][0]); initfence(ha[0][1]); initfence(ha[1][0]); initfence(ha[1][1]);
      #pragma unroll
      for (int kb = 0; kb < 256; kb += 32) {
        s16x8 av0 = *(const s16x8*)&Xs[aq + lr][kb + kg];
        s16x8 av1 = *(const s16x8*)&Xs[aq + 16 + lr][kb + kg];
        s16x8 bv0 = *(const s16x8*)&Ws[(bq + lr) * 264 + kb + kg];
        s16x8 bv1 = *(const s16x8*)&Ws[(bq + 16 + lr) * 264 + kb + kg];
        mfma16(ha[0][0], av0, bv0);
        mfma16(ha[0][1], av0, bv1);
        mfma16(ha[1][0], av1, bv0);
        mfma16(ha[1][1], av1, bv1);
      }
      accfence(ha[0][0]); accfence(ha[0][1]); accfence(ha[1][0]); accfence(ha[1][1]);
      #pragma unroll
      for (int n = 0; n < 2; ++n) {
        float bb = b1g[e * HID + hc + bq + n * 16 + lr];
        #pragma unroll
        for (int m = 0; m < 2; ++m) {
          #pragma unroll
          for (int q = 0; q < 4; ++q) {
            float hv = fmaxf(ha[m][n][q] + bb, 0.f);
            hs[aq + m * 16 + lg * 4 + q][bq + n * 16 + lr] = (short)f2bf(hv);
          }
        }
      }
    }
    __syncthreads();
    { // stage W2 chunk: Ws[d][0..63] = W2T[e][d][hc..hc+64]
      const unsigned short* src = W2T + (size_t)e * DIM * HID + hc;
      #pragma unroll
      for (int p = 0; p < 8; ++p) {
        int cc = tid + p * 256;
        int d = cc >> 3, col = (cc & 7) * 8;
        *(s16x8*)&Ws[d * 72 + col] = *(const s16x8*)(src + (size_t)d * HID + col);
      }
    }
    __syncthreads();
    { // GEMM2: acc += hs @ W2chunk   (wave w owns output cols [64w, 64w+64))
      #pragma unroll
      for (int kb = 0; kb < HC; kb += 32) {
        s16x8 a4[4], b4[4];
        #pragma unroll
        for (int m = 0; m < 4; ++m) a4[m] = *(const s16x8*)&hs[m * 16 + lr][kb + kg];
        #pragma unroll
        for (int n = 0; n < 4; ++n) b4[n] = *(const s16x8*)&Ws[(w * 64 + n * 16 + lr) * 72 + kb + kg];
        #pragma unroll
        for (int m = 0; m < 4; ++m) {
          #pragma unroll
          for (int n = 0; n < 4; ++n) mfma16(acc[m][n], a4[m], b4[n]);
        }
      }
    }
  }

  // epilogue: scatter-add (+b2 once, from slice 0)
  #pragma unroll
  for (int m = 0; m < 4; ++m) {
    #pragma unroll
    for (int n = 0; n < 4; ++n) accfence(acc[m][n]);
  }
  #pragma unroll
  for (int m = 0; m < 4; ++m) {
    #pragma unroll
    for (int q = 0; q < 4; ++q) {
      int lrow = m * 16 + lg * 4 + q;
      int grow = t * MTILE + lrow;
      if (grow < cnt) {
        int ntok = mylist[lrow];
        #pragma unroll
        for (int n = 0; n < 4; ++n) {
          int d = w * 64 + n * 16 + lr;
          float v = acc[m][n][q];
          if (s == 0) v += b2g[e * DIM + d];
          atomicAdd(out + (size_t)ntok * DIM + d, v);
        }
      }
    }
  }
}

extern "C" void kernel_launch(void* const* d_in, const int* in_sizes, int n_in,
                              void* d_out, int out_size, void* d_ws, size_t ws_size,
                              hipStream_t stream) {
  const float* x    = (const float*)d_in[0];
  const float* gW   = (const float*)d_in[1];
  const float* gb   = (const float*)d_in[2];
  const float* W1   = (const float*)d_in[3];
  const float* b1   = (const float*)d_in[4];
  const float* W2   = (const float*)d_in[5];
  const float* b2   = (const float*)d_in[6];
  const float* temp = (const float*)d_in[7];
  float* out = (float*)d_out;

  char* ws = (char*)d_ws;
  int*            counts = (int*)(ws + 0);                      // 256 B
  int*            list   = (int*)(ws + 256);                    // 8*4096*4 = 131072 B
  unsigned short* xbf    = (unsigned short*)(ws + 131584);      // 2 MB
  unsigned short* W1T    = (unsigned short*)(ws + 2228736);     // 4 MB
  unsigned short* W2T    = (unsigned short*)(ws + 6423040);     // 4 MB  (total ~10.2 MB)

  hipMemsetAsync(counts, 0, 256, stream);
  hipMemsetAsync(d_out, 0, (size_t)out_size * sizeof(float), stream);

  tr_cvt<<<dim3(HID/32, DIM/32, NEXP), dim3(32, 8, 1), 0, stream>>>(W1, W1T, DIM, HID);
  tr_cvt<<<dim3(DIM/32, HID/32, NEXP), dim3(32, 8, 1), 0, stream>>>(W2, W2T, HID, DIM);
  gate_route<<<NTOK/64, 256, 0, stream>>>(x, gW, gb, temp, counts, list, xbf);
  moe_ffn<<<NEXP * (NTOK/MTILE) * 2, 256, 0, stream>>>(xbf, W1T, W2T, b1, b2, counts, list, out);
}

// Round 3
// 86.816 us; speedup vs baseline: 1.9367x; 1.0898x over previous
//
#include <hip/hip_runtime.h>
#include <hip/hip_bf16.h>
#include <stdint.h>

#define NTOK 4096
#define DIM  256
#define HID  1024
#define NEXP 8
#define MTILE 32
#define HC 64
#define HSLICE 512
#define NSLICE 2

typedef float f32x4 __attribute__((ext_vector_type(4)));
typedef short s16x8 __attribute__((ext_vector_type(8)));

__device__ __forceinline__ unsigned short f2bf(float f) {
  union { float f; unsigned u; } v; v.f = f;
  unsigned r = v.u + 0x7FFFu + ((v.u >> 16) & 1u);
  return (unsigned short)(r >> 16);
}

__device__ __forceinline__ void mfma16(f32x4& acc, s16x8 a, s16x8 b) {
  asm("v_mfma_f32_16x16x32_bf16 %0, %1, %2, %0" : "+v"(acc) : "v"(a), "v"(b));
}
__device__ __forceinline__ void accfence(f32x4& a) {   // MFMA->VALU read hazard
  asm volatile("s_nop 7" : "+v"(a));
}
__device__ __forceinline__ void initfence(f32x4& a) {  // VALU init -> MFMA srcC hazard
  asm volatile("s_nop 1" : "+v"(a));
}

// ---- transpose + f32->bf16 : in [E][R][C] f32 -> out [E][C][R] bf16 ----
__global__ __launch_bounds__(256) void tr_cvt(const float* __restrict__ in,
                                              unsigned short* __restrict__ out,
                                              int R, int C) {
  __shared__ float tile[32][33];
  int e = blockIdx.z;
  int r0 = blockIdx.y * 32, c0 = blockIdx.x * 32;
  int tx = threadIdx.x, ty = threadIdx.y;
  const float* ip = in + (size_t)e * R * C;
  unsigned short* op = out + (size_t)e * R * C;
  #pragma unroll
  for (int k = 0; k < 4; ++k)
    tile[ty + 8*k][tx] = ip[(size_t)(r0 + ty + 8*k) * C + c0 + tx];
  __syncthreads();
  #pragma unroll
  for (int k = 0; k < 4; ++k)
    op[(size_t)(c0 + ty + 8*k) * R + r0 + tx] = f2bf(tile[tx][ty + 8*k]);
}

// ---- gate + top-2 + block-aggregated routing (16 tokens/block, 16 lanes/token) ----
__global__ __launch_bounds__(256) void gate_route(const float* __restrict__ x,
    const float* __restrict__ gW, const float* __restrict__ gb,
    const float* __restrict__ temp,
    int* __restrict__ counts, int* __restrict__ list,
    unsigned short* __restrict__ xbf) {
  __shared__ int pairs[16][2];
  __shared__ int lcnt[NEXP], lbase[NEXP], lrank[NEXP];
  int tid = threadIdx.x;
  int w = tid >> 6, lane = tid & 63;
  int sl = lane & 15, g = lane >> 4;
  if (tid < NEXP) { lcnt[tid] = 0; lrank[tid] = 0; }
  __syncthreads();
  int t0 = blockIdx.x * 16;
  int tok = w * 4 + g;
  int n = t0 + tok;

  float4 xv[4];
  #pragma unroll
  for (int p = 0; p < 4; ++p)
    xv[p] = *reinterpret_cast<const float4*>(x + (size_t)n * DIM + sl * 16 + p * 4);

  // x -> bf16 (16 values per lane, contiguous)
  {
    s16x8 xb0, xb1;
    xb0[0]=(short)f2bf(xv[0].x); xb0[1]=(short)f2bf(xv[0].y); xb0[2]=(short)f2bf(xv[0].z); xb0[3]=(short)f2bf(xv[0].w);
    xb0[4]=(short)f2bf(xv[1].x); xb0[5]=(short)f2bf(xv[1].y); xb0[6]=(short)f2bf(xv[1].z); xb0[7]=(short)f2bf(xv[1].w);
    xb1[0]=(short)f2bf(xv[2].x); xb1[1]=(short)f2bf(xv[2].y); xb1[2]=(short)f2bf(xv[2].z); xb1[3]=(short)f2bf(xv[2].w);
    xb1[4]=(short)f2bf(xv[3].x); xb1[5]=(short)f2bf(xv[3].y); xb1[6]=(short)f2bf(xv[3].z); xb1[7]=(short)f2bf(xv[3].w);
    *reinterpret_cast<s16x8*>(xbf + (size_t)n * DIM + sl * 16)     = xb0;
    *reinterpret_cast<s16x8*>(xbf + (size_t)n * DIM + sl * 16 + 8) = xb1;
  }

  float acc[NEXP];
  #pragma unroll
  for (int e = 0; e < NEXP; ++e) {
    const float* we = gW + (size_t)e * DIM + sl * 16;
    float a = 0.f;
    #pragma unroll
    for (int p = 0; p < 4; ++p) {
      float4 wv = *reinterpret_cast<const float4*>(we + p * 4);
      a += xv[p].x*wv.x + xv[p].y*wv.y + xv[p].z*wv.z + xv[p].w*wv.w;
    }
    acc[e] = a;
  }
  #pragma unroll
  for (int off = 1; off < 16; off <<= 1) {
    #pragma unroll
    for (int e = 0; e < NEXP; ++e) acc[e] += __shfl_xor(acc[e], off);
  }
  if (sl == 0) {
    float t = temp[0];
    float s[NEXP];
    #pragma unroll
    for (int e = 0; e < NEXP; ++e) s[e] = (acc[e] + gb[e]) / t;
    int b0 = 0; float v0 = s[0];
    #pragma unroll
    for (int e = 1; e < NEXP; ++e) if (s[e] > v0) { v0 = s[e]; b0 = e; }
    int b1i = 0; float v1 = -3.4e38f;
    #pragma unroll
    for (int e = 0; e < NEXP; ++e) if (e != b0 && s[e] > v1) { v1 = s[e]; b1i = e; }
    pairs[tok][0] = b0;
    pairs[tok][1] = b1i;
    atomicAdd(&lcnt[b0], 1);
    atomicAdd(&lcnt[b1i], 1);
  }
  __syncthreads();
  if (tid < NEXP) lbase[tid] = atomicAdd(&counts[tid], lcnt[tid]);
  __syncthreads();
  if (tid < 32) {
    int tk = tid >> 1;
    int e = pairs[tk][tid & 1];
    int r = atomicAdd(&lrank[e], 1);
    list[e * NTOK + lbase[e] + r] = t0 + tk;
  }
}

// ---- fused per-expert FFN: weights direct global->VGPR, X/h in LDS ----
__global__ __launch_bounds__(256, 3) void moe_ffn(
    const unsigned short* __restrict__ xbf,
    const unsigned short* __restrict__ W1T,  // [E][H][D] bf16
    const unsigned short* __restrict__ W2T,  // [E][D][H] bf16
    const float* __restrict__ b1g, const float* __restrict__ b2g,
    const int* __restrict__ counts, const int* __restrict__ list,
    float* __restrict__ out) {
  int b = blockIdx.x;
  int e = b & 7;
  int r = b >> 3;
  int s = r & 1;
  int t = r >> 1;
  int cnt = counts[e];
  if (t * MTILE >= cnt) return;

  __shared__ __align__(16) short Xs[32][264];
  __shared__ __align__(16) short hs[32][72];

  int tid = threadIdx.x;
  int l = tid & 63, w = tid >> 6;
  int lr = l & 15, lg = l >> 4, kg = lg * 8;
  const int* mylist = list + e * NTOK + t * MTILE;

  // stage gathered X tile (32 x 256 bf16)
  #pragma unroll
  for (int p = 0; p < 4; ++p) {
    int c = tid + p * 256;
    int row = c >> 5, col = (c & 31) * 8;
    int grow = t * MTILE + row;
    int ntok = (grow < cnt) ? mylist[row] : 0;
    *(s16x8*)&Xs[row][col] = *(const s16x8*)(xbf + (size_t)ntok * DIM + col);
  }

  f32x4 acc[2][4] = {};
  const unsigned short* W1e = W1T + (size_t)e * HID * DIM;
  const unsigned short* W2e = W2T + (size_t)e * DIM * HID;
  int hbase = s * HSLICE;

  __syncthreads();

  for (int c = 0; c < HSLICE / HC; ++c) {
    int hc = hbase + c * HC;
    // GEMM1: 32 tokens x 64 h-cols (wave w: cols w*16+lr), k = 256
    f32x4 ha[2] = {};
    initfence(ha[0]); initfence(ha[1]);
    const unsigned short* bsrc = W1e + (size_t)(hc + w * 16 + lr) * DIM + kg;
    #pragma unroll
    for (int kb = 0; kb < 8; ++kb) {
      s16x8 bv = *(const s16x8*)(bsrc + kb * 32);
      s16x8 a0 = *(const s16x8*)&Xs[lr][kb * 32 + kg];
      s16x8 a1 = *(const s16x8*)&Xs[16 + lr][kb * 32 + kg];
      mfma16(ha[0], a0, bv);
      mfma16(ha[1], a1, bv);
    }
    accfence(ha[0]); accfence(ha[1]);
    float bb = b1g[e * HID + hc + w * 16 + lr];
    #pragma unroll
    for (int m = 0; m < 2; ++m) {
      #pragma unroll
      for (int q = 0; q < 4; ++q) {
        float hv = fmaxf(ha[m][q] + bb, 0.f);
        hs[m * 16 + lg * 4 + q][w * 16 + lr] = (short)f2bf(hv);
      }
    }
    __syncthreads();
    // GEMM2: 32 tokens x 256 d (wave w: cols w*64..), k = 64
    #pragma unroll
    for (int kb = 0; kb < 2; ++kb) {
      s16x8 a0 = *(const s16x8*)&hs[lr][kb * 32 + kg];
      s16x8 a1 = *(const s16x8*)&hs[16 + lr][kb * 32 + kg];
      #pragma unroll
      for (int n = 0; n < 4; ++n) {
        s16x8 bv = *(const s16x8*)(W2e + (size_t)(w * 64 + n * 16 + lr) * HID + hc + kb * 32 + kg);
        mfma16(acc[0][n], a0, bv);
        mfma16(acc[1][n], a1, bv);
      }
    }
    __syncthreads();  // before next chunk overwrites hs
  }

  #pragma unroll
  for (int m = 0; m < 2; ++m) {
    #pragma unroll
    for (int n = 0; n < 4; ++n) accfence(acc[m][n]);
  }
  #pragma unroll
  for (int m = 0; m < 2; ++m) {
    #pragma unroll
    for (int q = 0; q < 4; ++q) {
      int lrow = m * 16 + lg * 4 + q;
      int grow = t * MTILE + lrow;
      if (grow < cnt) {
        int ntok = mylist[lrow];
        #pragma unroll
        for (int n = 0; n < 4; ++n) {
          int d = w * 64 + n * 16 + lr;
          float v = acc[m][n][q];
          if (s == 0) v += b2g[e * DIM + d];
          atomicAdd(out + (size_t)ntok * DIM + d, v);
        }
      }
    }
  }
}

extern "C" void kernel_launch(void* const* d_in, const int* in_sizes, int n_in,
                              void* d_out, int out_size, void* d_ws, size_t ws_size,
                              hipStream_t stream) {
  const float* x    = (const float*)d_in[0];
  const float* gW   = (const float*)d_in[1];
  const float* gb   = (const float*)d_in[2];
  const float* W1   = (const float*)d_in[3];
  const float* b1   = (const float*)d_in[4];
  const float* W2   = (const float*)d_in[5];
  const float* b2   = (const float*)d_in[6];
  const float* temp = (const float*)d_in[7];
  float* out = (float*)d_out;

  char* ws = (char*)d_ws;
  int*            counts = (int*)(ws + 0);                      // 256 B
  int*            list   = (int*)(ws + 256);                    // 131072 B
  unsigned short* xbf    = (unsigned short*)(ws + 131584);      // 2 MB
  unsigned short* W1T    = (unsigned short*)(ws + 2228736);     // 4 MB
  unsigned short* W2T    = (unsigned short*)(ws + 6423040);     // 4 MB

  hipMemsetAsync(counts, 0, 256, stream);
  hipMemsetAsync(d_out, 0, (size_t)out_size * sizeof(float), stream);

  tr_cvt<<<dim3(HID/32, DIM/32, NEXP), dim3(32, 8, 1), 0, stream>>>(W1, W1T, DIM, HID);
  tr_cvt<<<dim3(DIM/32, HID/32, NEXP), dim3(32, 8, 1), 0, stream>>>(W2, W2T, HID, DIM);
  gate_route<<<NTOK/16, 256, 0, stream>>>(x, gW, gb, temp, counts, list, xbf);
  moe_ffn<<<NEXP * (NTOK/MTILE) * NSLICE, 256, 0, stream>>>(xbf, W1T, W2T, b1, b2, counts, list, out);
}